// Round 1
// baseline (299.590 us; speedup 1.0000x reference)
//
#include <hip/hip_runtime.h>
#include <hip/hip_bf16.h>
#include <stdint.h>

using short8 = __attribute__((ext_vector_type(8))) short;
using f32x4  = __attribute__((ext_vector_type(4))) float;

static constexpr int EMBED = 768;
static constexpr int NH    = 12;
static constexpr int HD    = 64;
static constexpr int BB    = 4;
static constexpr int NN    = 2048;
static constexpr int MROWS = BB * NN;          // 8192
static constexpr int QKV_COLS = 3 * EMBED;     // 2304
static constexpr float ATT_SCALE = 0.125f;     // HD^-0.5

// round-to-nearest-even fp32 -> bf16 (no NaNs in this workload)
__device__ __forceinline__ short f2bs(float f) {
  unsigned int u = __float_as_uint(f);
  u += 0x7fffu + ((u >> 16) & 1u);
  return (short)(u >> 16);
}

__device__ __forceinline__ void gload_lds16(const void* g, void* l) {
  __builtin_amdgcn_global_load_lds(
      (const __attribute__((address_space(1))) unsigned int*)g,
      (__attribute__((address_space(3))) unsigned int*)l, 16, 0, 0);
}

// ---------------- fp32 -> bf16 bulk convert (x) ----------------
__global__ void k_cvt(const float* __restrict__ in, short* __restrict__ out, int n8) {
  int i = blockIdx.x * blockDim.x + threadIdx.x;
  if (i >= n8) return;
  const float4* p = reinterpret_cast<const float4*>(in) + (size_t)i * 2;
  float4 a = p[0], b = p[1];
  short8 o;
  o[0] = f2bs(a.x); o[1] = f2bs(a.y); o[2] = f2bs(a.z); o[3] = f2bs(a.w);
  o[4] = f2bs(b.x); o[5] = f2bs(b.y); o[6] = f2bs(b.z); o[7] = f2bs(b.w);
  reinterpret_cast<short8*>(out)[i] = o;
}

// ---------------- fp32 [K][NC] -> bf16 [NC][K] transpose ----------------
__global__ void k_transpose_cvt(const float* __restrict__ in, short* __restrict__ out,
                                int K, int NC) {
  __shared__ float t[32][33];
  int n0 = blockIdx.x * 32, k0 = blockIdx.y * 32;
  t[threadIdx.y][threadIdx.x] = in[(size_t)(k0 + threadIdx.y) * NC + n0 + threadIdx.x];
  __syncthreads();
  out[(size_t)(n0 + threadIdx.y) * K + k0 + threadIdx.x] = f2bs(t[threadIdx.x][threadIdx.y]);
}

// ---------------- bf16 GEMM, C = A[M][K] * Bt[N][K]^T + bias ----------------
// EPI 0: scatter into Q(prescaled)/K/V [B,H,N,hd] bf16 buffers
// EPI 1: fp32 store to out[M][NC]
template <int EPI>
__global__ __launch_bounds__(256)
void k_gemm_bt(const short* __restrict__ A, const short* __restrict__ Bt,
               const float* __restrict__ bias,
               short* __restrict__ q_out, short* __restrict__ k_out,
               short* __restrict__ v_out, float* __restrict__ f_out,
               int M, int NC, int K) {
  __shared__ short sA[128][32];
  __shared__ short sB[128][32];
  int tid = threadIdx.x;
  int lane = tid & 63, wid = tid >> 6;
  int wr = wid >> 1, wc = wid & 1;
  int l15 = lane & 15, l4 = lane >> 4;
  int mtile = blockIdx.x * 128, ntile = blockIdx.y * 128;

  f32x4 acc[4][4];
#pragma unroll
  for (int i = 0; i < 4; ++i)
#pragma unroll
    for (int j = 0; j < 4; ++j) acc[i][j] = (f32x4){0.f, 0.f, 0.f, 0.f};

  const int rA = lane >> 2;        // 0..15 row within 16-row slab
  const int cA = (lane & 3) * 8;   // k-chunk

  for (int kk = 0; kk < K; kk += 32) {
    __syncthreads();
#pragma unroll
    for (int p = 0; p < 2; ++p) {
      int r0 = p * 64 + wid * 16;
      gload_lds16(A  + (size_t)(mtile + r0 + rA) * K + kk + cA, &sA[r0][0]);
      gload_lds16(Bt + (size_t)(ntile + r0 + rA) * K + kk + cA, &sB[r0][0]);
    }
    __syncthreads();
    short8 af[4], bfr[4];
#pragma unroll
    for (int i = 0; i < 4; ++i)
      af[i] = *reinterpret_cast<const short8*>(&sA[wr * 64 + i * 16 + l15][l4 * 8]);
#pragma unroll
    for (int j = 0; j < 4; ++j)
      bfr[j] = *reinterpret_cast<const short8*>(&sB[wc * 64 + j * 16 + l15][l4 * 8]);
#pragma unroll
    for (int i = 0; i < 4; ++i)
#pragma unroll
      for (int j = 0; j < 4; ++j)
        acc[i][j] = __builtin_amdgcn_mfma_f32_16x16x32_bf16(af[i], bfr[j], acc[i][j], 0, 0, 0);
  }

#pragma unroll
  for (int i = 0; i < 4; ++i) {
#pragma unroll
    for (int j = 0; j < 4; ++j) {
#pragma unroll
      for (int r = 0; r < 4; ++r) {
        int row = mtile + wr * 64 + i * 16 + l4 * 4 + r;
        int col = ntile + wc * 64 + j * 16 + l15;
        float v = acc[i][j][r] + bias[col];
        if (EPI == 0) {
          int s = col / EMBED;
          int rem = col - s * EMBED;
          int h = rem >> 6, d = rem & 63;
          int b = row >> 11, n = row & 2047;
          if (s == 0) v *= ATT_SCALE;
          short* dst = (s == 0) ? q_out : (s == 1 ? k_out : v_out);
          dst[(size_t)((b * NH + h) * NN + n) * HD + d] = f2bs(v);
        } else {
          f_out[(size_t)row * NC + col] = v;
        }
      }
    }
  }
}

// ---------------- flash attention ----------------
// grid (N/128, B*H); 4 waves/block, 32 q-rows per wave, KVBLK=64
__global__ __launch_bounds__(256)
void k_attn(const short* __restrict__ qb, const short* __restrict__ kb,
            const short* __restrict__ vb, short* __restrict__ ob) {
  __shared__ short sK[64 * 64];   // [kv][c], XOR-swizzled rows
  __shared__ short sV[64 * 64];   // V^T: [d][kv], XOR-swizzled rows
  __shared__ short sP[128 * 64];  // per-wave 32-row slabs, swizzled

  int tid = threadIdx.x, lane = tid & 63, wid = tid >> 6;
  int l15 = lane & 15, l4 = lane >> 4;
  int bh = blockIdx.y;
  int b = bh / NH, h = bh % NH;
  int qtile = blockIdx.x * 128;
  int qr0 = qtile + wid * 32;

  const short* Q  = qb + (size_t)bh * NN * HD;
  const short* Kp = kb + (size_t)bh * NN * HD;
  const short* Vp = vb + (size_t)bh * NN * HD;

  // hoisted Q fragments: rows qr0 + mt*16 + l15, k-chunks c*32 + l4*8
  short8 qf[2][2];
#pragma unroll
  for (int mt = 0; mt < 2; ++mt)
#pragma unroll
    for (int c = 0; c < 2; ++c)
      qf[mt][c] = *reinterpret_cast<const short8*>(
          Q + (size_t)(qr0 + mt * 16 + l15) * HD + c * 32 + l4 * 8);

  f32x4 o_acc[2][4];
  float m_run[2][4], l_run[2][4];
#pragma unroll
  for (int mt = 0; mt < 2; ++mt) {
#pragma unroll
    for (int dt = 0; dt < 4; ++dt) o_acc[mt][dt] = (f32x4){0.f, 0.f, 0.f, 0.f};
#pragma unroll
    for (int r = 0; r < 4; ++r) { m_run[mt][r] = -1e30f; l_run[mt][r] = 0.f; }
  }

  for (int kv0 = 0; kv0 < NN; kv0 += 64) {
    __syncthreads();
    // stage K rows + V^T (transposed scatter), both swizzled
#pragma unroll
    for (int p = 0; p < 2; ++p) {
      int idx = tid + p * 256;
      int r = idx >> 3, c = idx & 7;
      short8 kr = *reinterpret_cast<const short8*>(Kp + (size_t)(kv0 + r) * HD + c * 8);
      *reinterpret_cast<short8*>(&sK[r * 64 + ((c ^ (r & 7)) << 3)]) = kr;
      short8 vr = *reinterpret_cast<const short8*>(Vp + (size_t)(kv0 + r) * HD + c * 8);
#pragma unroll
      for (int e = 0; e < 8; ++e) {
        int d = c * 8 + e;  // dest row in V^T, kv = r dest col
        sV[d * 64 + (((r >> 3) ^ (d & 7)) << 3) + (r & 7)] = vr[e];
      }
    }
    __syncthreads();

    // S = Q K^T : D[q][kv], per wave 32x64
    f32x4 s_acc[2][4];
#pragma unroll
    for (int mt = 0; mt < 2; ++mt)
#pragma unroll
      for (int nt = 0; nt < 4; ++nt) s_acc[mt][nt] = (f32x4){0.f, 0.f, 0.f, 0.f};
#pragma unroll
    for (int c = 0; c < 2; ++c) {
      short8 kf[4];
#pragma unroll
      for (int nt = 0; nt < 4; ++nt) {
        int rowk = nt * 16 + l15;
        int chunk = (c * 4 + l4) ^ (rowk & 7);
        kf[nt] = *reinterpret_cast<const short8*>(&sK[rowk * 64 + (chunk << 3)]);
      }
#pragma unroll
      for (int mt = 0; mt < 2; ++mt)
#pragma unroll
        for (int nt = 0; nt < 4; ++nt)
          s_acc[mt][nt] = __builtin_amdgcn_mfma_f32_16x16x32_bf16(qf[mt][c], kf[nt],
                                                                  s_acc[mt][nt], 0, 0, 0);
    }

    // online softmax (rows live in (l4,r); 16 kv-lanes reduced via shfl_xor)
#pragma unroll
    for (int mt = 0; mt < 2; ++mt) {
#pragma unroll
      for (int r = 0; r < 4; ++r) {
        float mx = fmaxf(fmaxf(s_acc[mt][0][r], s_acc[mt][1][r]),
                         fmaxf(s_acc[mt][2][r], s_acc[mt][3][r]));
#pragma unroll
        for (int msk = 1; msk < 16; msk <<= 1) mx = fmaxf(mx, __shfl_xor(mx, msk));
        float mold = m_run[mt][r];
        float mnew = fmaxf(mold, mx);
        float scale = __expf(mold - mnew);
        float psum = 0.f;
#pragma unroll
        for (int nt = 0; nt < 4; ++nt) {
          float p = __expf(s_acc[mt][nt][r] - mnew);
          s_acc[mt][nt][r] = p;
          psum += p;
        }
#pragma unroll
        for (int msk = 1; msk < 16; msk <<= 1) psum += __shfl_xor(psum, msk);
        m_run[mt][r] = mnew;
        l_run[mt][r] = l_run[mt][r] * scale + psum;
#pragma unroll
        for (int dt = 0; dt < 4; ++dt) {
          o_acc[mt][dt][0] = o_acc[mt][dt][0]; // keep shape
          o_acc[mt][dt][r] *= scale;
        }
      }
    }

    // P -> LDS (bf16, swizzled); per-wave slab so no barrier needed
#pragma unroll
    for (int mt = 0; mt < 2; ++mt)
#pragma unroll
      for (int nt = 0; nt < 4; ++nt)
#pragma unroll
        for (int r = 0; r < 4; ++r) {
          int row = wid * 32 + mt * 16 + l4 * 4 + r;
          int col = nt * 16 + l15;
          sP[row * 64 + (((col >> 3) ^ (row & 7)) << 3) + (col & 7)] =
              f2bs(s_acc[mt][nt][r]);
        }

    // O += P V : A = P[32][64] from LDS, B = V via V^T rows
#pragma unroll
    for (int c = 0; c < 2; ++c) {
      short8 pf[2], vf[4];
#pragma unroll
      for (int mt = 0; mt < 2; ++mt) {
        int row = wid * 32 + mt * 16 + l15;
        int chunk = (c * 4 + l4) ^ (row & 7);
        pf[mt] = *reinterpret_cast<const short8*>(&sP[row * 64 + (chunk << 3)]);
      }
#pragma unroll
      for (int dt = 0; dt < 4; ++dt) {
        int row = dt * 16 + l15;
        int chunk = (c * 4 + l4) ^ (row & 7);
        vf[dt] = *reinterpret_cast<const short8*>(&sV[row * 64 + (chunk << 3)]);
      }
#pragma unroll
      for (int mt = 0; mt < 2; ++mt)
#pragma unroll
        for (int dt = 0; dt < 4; ++dt)
          o_acc[mt][dt] = __builtin_amdgcn_mfma_f32_16x16x32_bf16(pf[mt], vf[dt],
                                                                  o_acc[mt][dt], 0, 0, 0);
    }
  }

  // normalize + store to [B,N,H*hd] bf16
#pragma unroll
  for (int mt = 0; mt < 2; ++mt) {
#pragma unroll
    for (int r = 0; r < 4; ++r) {
      float inv = 1.f / l_run[mt][r];
      int n = qr0 + mt * 16 + l4 * 4 + r;
#pragma unroll
      for (int dt = 0; dt < 4; ++dt)
        ob[(size_t)(b * NN + n) * EMBED + h * HD + dt * 16 + l15] =
            f2bs(o_acc[mt][dt][r] * inv);
    }
  }
}

extern "C" void kernel_launch(void* const* d_in, const int* in_sizes, int n_in,
                              void* d_out, int out_size, void* d_ws, size_t ws_size,
                              hipStream_t stream) {
  const float* x     = (const float*)d_in[0];
  const float* Wqkv  = (const float*)d_in[1];
  const float* bqkv  = (const float*)d_in[2];
  const float* Wproj = (const float*)d_in[3];
  const float* bproj = (const float*)d_in[4];
  float* out = (float*)d_out;

  // workspace layout (bf16 stored as short)
  char* ws = (char*)d_ws;
  const size_t SZ_X  = (size_t)MROWS * EMBED * 2;        // 12.58 MB
  const size_t SZ_WQ = (size_t)QKV_COLS * EMBED * 2;     // 3.54 MB
  const size_t SZ_WP = (size_t)EMBED * EMBED * 2;        // 1.18 MB
  const size_t SZ_HB = (size_t)BB * NH * NN * HD * 2;    // 12.58 MB each
  if (ws_size < SZ_X * 2 + SZ_WQ + SZ_WP + SZ_HB * 3) return;

  short* xb     = (short*)ws;            ws += SZ_X;
  short* wqkvT  = (short*)ws;            ws += SZ_WQ;
  short* wprojT = (short*)ws;            ws += SZ_WP;
  short* qbuf   = (short*)ws;            ws += SZ_HB;
  short* kbuf   = (short*)ws;            ws += SZ_HB;
  short* vbuf   = (short*)ws;            ws += SZ_HB;
  short* aout   = (short*)ws;            ws += SZ_X;

  int n8 = MROWS * EMBED / 8;
  k_cvt<<<(n8 + 255) / 256, 256, 0, stream>>>(x, xb, n8);
  k_transpose_cvt<<<dim3(QKV_COLS / 32, EMBED / 32), dim3(32, 32), 0, stream>>>(
      Wqkv, wqkvT, EMBED, QKV_COLS);
  k_transpose_cvt<<<dim3(EMBED / 32, EMBED / 32), dim3(32, 32), 0, stream>>>(
      Wproj, wprojT, EMBED, EMBED);
  k_gemm_bt<0><<<dim3(MROWS / 128, QKV_COLS / 128), 256, 0, stream>>>(
      xb, wqkvT, bqkv, qbuf, kbuf, vbuf, nullptr, MROWS, QKV_COLS, EMBED);
  k_attn<<<dim3(NN / 128, BB * NH), 256, 0, stream>>>(qbuf, kbuf, vbuf, aout);
  k_gemm_bt<1><<<dim3(MROWS / 128, EMBED / 128), 256, 0, stream>>>(
      aout, wprojT, bproj, nullptr, nullptr, nullptr, out, MROWS, EMBED, EMBED);
}

// Round 3
// 213.822 us; speedup vs baseline: 1.4011x; 1.4011x over previous
//
#include <hip/hip_runtime.h>
#include <hip/hip_bf16.h>
#include <stdint.h>

using short4v = __attribute__((ext_vector_type(4))) short;
using short8  = __attribute__((ext_vector_type(8))) short;
using f32x4   = __attribute__((ext_vector_type(4))) float;

static constexpr int EMBED = 768;
static constexpr int NH    = 12;
static constexpr int HD    = 64;
static constexpr int BB    = 4;
static constexpr int NN    = 2048;
static constexpr int MROWS = BB * NN;          // 8192
static constexpr int QKV_COLS = 3 * EMBED;     // 2304
static constexpr float ATT_SCALE = 0.125f;     // HD^-0.5

// round-to-nearest-even fp32 -> bf16
__device__ __forceinline__ short f2bs(float f) {
  unsigned int u = __float_as_uint(f);
  u += 0x7fffu + ((u >> 16) & 1u);
  return (short)(u >> 16);
}

// pack two fp32 -> two bf16 in a u32 (lo at low address when stored LE)
__device__ __forceinline__ unsigned int pk2(float lo, float hi) {
  return (unsigned int)(unsigned short)f2bs(lo) |
         ((unsigned int)(unsigned short)f2bs(hi) << 16);
}

__device__ __forceinline__ void gload_lds16(const void* g, void* l) {
  __builtin_amdgcn_global_load_lds(
      (const __attribute__((address_space(1))) unsigned int*)g,
      (__attribute__((address_space(3))) unsigned int*)l, 16, 0, 0);
}

// ---------------- fp32 -> bf16 bulk convert (x) ----------------
__global__ void k_cvt(const float* __restrict__ in, short* __restrict__ out, int n8) {
  int i = blockIdx.x * blockDim.x + threadIdx.x;
  if (i >= n8) return;
  const float4* p = reinterpret_cast<const float4*>(in) + (size_t)i * 2;
  float4 a = p[0], b = p[1];
  short8 o;
  o[0] = f2bs(a.x); o[1] = f2bs(a.y); o[2] = f2bs(a.z); o[3] = f2bs(a.w);
  o[4] = f2bs(b.x); o[5] = f2bs(b.y); o[6] = f2bs(b.z); o[7] = f2bs(b.w);
  reinterpret_cast<short8*>(out)[i] = o;
}

// ---------------- fp32 [K][NC] -> bf16 [NC][K] transpose ----------------
__global__ void k_transpose_cvt(const float* __restrict__ in, short* __restrict__ out,
                                int K, int NC) {
  __shared__ float t[32][33];
  int n0 = blockIdx.x * 32, k0 = blockIdx.y * 32;
  t[threadIdx.y][threadIdx.x] = in[(size_t)(k0 + threadIdx.y) * NC + n0 + threadIdx.x];
  __syncthreads();
  out[(size_t)(n0 + threadIdx.y) * K + k0 + threadIdx.x] = f2bs(t[threadIdx.x][threadIdx.y]);
}

// ---------------- bf16 GEMM, C = A[M][K] * Bt[N][K]^T + bias ----------------
// EPI 0: scatter into Q(prescaled)/K [B,H,N,hd] and V^T [B,H,hd,N] bf16 buffers
// EPI 1: fp32 store to out[M][NC]
template <int EPI>
__global__ __launch_bounds__(256)
void k_gemm_bt(const short* __restrict__ A, const short* __restrict__ Bt,
               const float* __restrict__ bias,
               short* __restrict__ q_out, short* __restrict__ k_out,
               short* __restrict__ vT_out, float* __restrict__ f_out,
               int M, int NC, int K) {
  __shared__ short sA[128][32];
  __shared__ short sB[128][32];
  int tid = threadIdx.x;
  int lane = tid & 63, wid = tid >> 6;
  int wr = wid >> 1, wc = wid & 1;
  int l15 = lane & 15, l4 = lane >> 4;
  int mtile = blockIdx.x * 128, ntile = blockIdx.y * 128;

  f32x4 acc[4][4];
#pragma unroll
  for (int i = 0; i < 4; ++i)
#pragma unroll
    for (int j = 0; j < 4; ++j) acc[i][j] = (f32x4){0.f, 0.f, 0.f, 0.f};

  const int rA = lane >> 2;        // 0..15 row within 16-row slab
  const int cA = (lane & 3) * 8;   // k-chunk

  for (int kk = 0; kk < K; kk += 32) {
    __syncthreads();
#pragma unroll
    for (int p = 0; p < 2; ++p) {
      int r0 = p * 64 + wid * 16;
      gload_lds16(A  + (size_t)(mtile + r0 + rA) * K + kk + cA, &sA[r0][0]);
      gload_lds16(Bt + (size_t)(ntile + r0 + rA) * K + kk + cA, &sB[r0][0]);
    }
    __syncthreads();
    short8 af[4], bfr[4];
#pragma unroll
    for (int i = 0; i < 4; ++i)
      af[i] = *reinterpret_cast<const short8*>(&sA[wr * 64 + i * 16 + l15][l4 * 8]);
#pragma unroll
    for (int j = 0; j < 4; ++j)
      bfr[j] = *reinterpret_cast<const short8*>(&sB[wc * 64 + j * 16 + l15][l4 * 8]);
#pragma unroll
    for (int i = 0; i < 4; ++i)
#pragma unroll
      for (int j = 0; j < 4; ++j)
        acc[i][j] = __builtin_amdgcn_mfma_f32_16x16x32_bf16(af[i], bfr[j], acc[i][j], 0, 0, 0);
  }

#pragma unroll
  for (int i = 0; i < 4; ++i) {
#pragma unroll
    for (int j = 0; j < 4; ++j) {
      int col = ntile + wc * 64 + j * 16 + l15;
      float bcol = bias[col];
      float vv[4];
#pragma unroll
      for (int r = 0; r < 4; ++r) vv[r] = acc[i][j][r] + bcol;
      if (EPI == 0) {
        int s = col / EMBED;                 // wave-uniform per block
        int rem = col - s * EMBED;
        int hh = rem >> 6, d = rem & 63;
        int row0 = mtile + wr * 64 + i * 16 + l4 * 4;
        int b2 = row0 >> 11, n0 = row0 & 2047;
        if (s == 0) {
#pragma unroll
          for (int r = 0; r < 4; ++r)
            q_out[(size_t)((b2 * NH + hh) * NN + n0 + r) * HD + d] =
                f2bs(vv[r] * ATT_SCALE);
        } else if (s == 1) {
#pragma unroll
          for (int r = 0; r < 4; ++r)
            k_out[(size_t)((b2 * NH + hh) * NN + n0 + r) * HD + d] = f2bs(vv[r]);
        } else {
          short4v o;
#pragma unroll
          for (int r = 0; r < 4; ++r) o[r] = f2bs(vv[r]);
          *reinterpret_cast<short4v*>(
              &vT_out[((size_t)(b2 * NH + hh) * HD + d) * NN + n0]) = o;
        }
      } else {
        int row0 = mtile + wr * 64 + i * 16 + l4 * 4;
#pragma unroll
        for (int r = 0; r < 4; ++r)
          f_out[(size_t)(row0 + r) * NC + col] = vv[r];
      }
    }
  }
}

// ---------------- flash attention (swapped-QK^T, O^T accum) ----------------
// grid (N/128, B*H); 4 waves, 32 q-rows/wave, KVBLK=64, double-buffered K/V^T
__global__ __launch_bounds__(256)
void k_attn(const short* __restrict__ qb, const short* __restrict__ kb,
            const short* __restrict__ vtb, short* __restrict__ ob) {
  __shared__ __align__(16) short sK[2][64 * 64];   // [kv][d], src-pre-swizzled
  __shared__ __align__(16) short sV[2][64 * 64];   // V^T [d][kv], src-pre-swizzled
  __shared__ __align__(16) short sP[4][32 * 64];   // per-wave P[q][kv], swizzled

  const int tid = threadIdx.x, lane = tid & 63, wid = tid >> 6;
  const int l15 = lane & 15, l4 = lane >> 4;
  const int bh = blockIdx.y, b = bh / NH, h = bh % NH;
  const int qr0 = blockIdx.x * 128 + wid * 32;

  const short* Q  = qb  + (size_t)bh * NN * HD;
  const short* Kp = kb  + (size_t)bh * NN * HD;
  const short* Vt = vtb + (size_t)bh * HD * NN;

  const int sr  = lane >> 3;   // staging: row within 8-row slab
  const int sc8 = lane & 7;    // staging: dest chunk

  // Q fragments (B-operand): q = qr0+mt*16+l15, k = c*32+l4*8..+8
  short8 qf[2][2];
#pragma unroll
  for (int mt = 0; mt < 2; ++mt)
#pragma unroll
    for (int c = 0; c < 2; ++c)
      qf[mt][c] = *reinterpret_cast<const short8*>(
          Q + (size_t)(qr0 + mt * 16 + l15) * HD + c * 32 + l4 * 8);

  f32x4 oT[2][4];
  float m_run[2], l_run[2];
#pragma unroll
  for (int mt = 0; mt < 2; ++mt) {
    m_run[mt] = -1e30f; l_run[mt] = 0.f;
#pragma unroll
    for (int dt = 0; dt < 4; ++dt) oT[mt][dt] = (f32x4){0.f, 0.f, 0.f, 0.f};
  }

#define STAGE(BUF, KV0)                                                          \
  {                                                                              \
    _Pragma("unroll")                                                            \
    for (int i_ = 0; i_ < 2; ++i_) {                                             \
      int r_ = wid * 16 + i_ * 8 + sr;                                           \
      int cs_ = (sc8 ^ (r_ & 7)) << 3;                                           \
      gload_lds16(Kp + (size_t)((KV0) + r_) * HD + cs_,                          \
                  &sK[BUF][(wid * 16 + i_ * 8) * 64]);                           \
      gload_lds16(Vt + (size_t)r_ * NN + (KV0) + cs_,                            \
                  &sV[BUF][(wid * 16 + i_ * 8) * 64]);                           \
    }                                                                            \
  }

  int cur = 0;
  STAGE(0, 0);
  __syncthreads();

  for (int t = 0; t < NN / 64; ++t) {
    if (t + 1 < NN / 64) STAGE(cur ^ 1, (t + 1) * 64);

    // S^T = mfma(K rows, Q rows): sa[mt][nt][r] = S[q=mt*16+l15][kv=nt*16+l4*4+r]
    f32x4 sa[2][4];
#pragma unroll
    for (int mt = 0; mt < 2; ++mt)
#pragma unroll
      for (int nt = 0; nt < 4; ++nt) sa[mt][nt] = (f32x4){0.f, 0.f, 0.f, 0.f};
#pragma unroll
    for (int c = 0; c < 2; ++c) {
      short8 kf[4];
#pragma unroll
      for (int nt = 0; nt < 4; ++nt) {
        int row = nt * 16 + l15;
        kf[nt] = *reinterpret_cast<const short8*>(
            &sK[cur][row * 64 + (((c * 4 + l4) ^ (row & 7)) << 3)]);
      }
#pragma unroll
      for (int mt = 0; mt < 2; ++mt)
#pragma unroll
        for (int nt = 0; nt < 4; ++nt)
          sa[mt][nt] = __builtin_amdgcn_mfma_f32_16x16x32_bf16(
              kf[nt], qf[mt][c], sa[mt][nt], 0, 0, 0);
    }

    // online softmax: lane owns q = mt*16+l15; 16 regs + 2 shuffles (l4 dim)
#pragma unroll
    for (int mt = 0; mt < 2; ++mt) {
      float mx = sa[mt][0][0];
#pragma unroll
      for (int nt = 0; nt < 4; ++nt)
#pragma unroll
        for (int r = 0; r < 4; ++r) mx = fmaxf(mx, sa[mt][nt][r]);
      mx = fmaxf(mx, __shfl_xor(mx, 16));
      mx = fmaxf(mx, __shfl_xor(mx, 32));
      float mnew = fmaxf(m_run[mt], mx);
      float sc = __expf(m_run[mt] - mnew);
      float ps = 0.f;
#pragma unroll
      for (int nt = 0; nt < 4; ++nt)
#pragma unroll
        for (int r = 0; r < 4; ++r) {
          float p = __expf(sa[mt][nt][r] - mnew);
          sa[mt][nt][r] = p;
          ps += p;
        }
      ps += __shfl_xor(ps, 16);
      ps += __shfl_xor(ps, 32);
      m_run[mt] = mnew;
      l_run[mt] = l_run[mt] * sc + ps;
#pragma unroll
      for (int dt = 0; dt < 4; ++dt) {
        oT[mt][dt][0] *= sc; oT[mt][dt][1] *= sc;
        oT[mt][dt][2] *= sc; oT[mt][dt][3] *= sc;
      }
      // P[q][kv] -> sP (bf16, packed 8B writes, 16B-chunk-swizzled by q&7)
      int q = mt * 16 + l15;
#pragma unroll
      for (int nt = 0; nt < 4; ++nt) {
        uint2 wv;
        wv.x = pk2(sa[mt][nt][0], sa[mt][nt][1]);
        wv.y = pk2(sa[mt][nt][2], sa[mt][nt][3]);
        int ch = (nt * 2 + (l4 >> 1)) ^ (q & 7);
        *reinterpret_cast<uint2*>(
            (char*)&sP[wid][0] + q * 128 + ch * 16 + (l4 & 1) * 8) = wv;
      }
    }

    // O^T += mfma(V^T rows, P rows)
#pragma unroll
    for (int c = 0; c < 2; ++c) {
      short8 vf[4], pf[2];
#pragma unroll
      for (int dt = 0; dt < 4; ++dt) {
        int row = dt * 16 + l15;
        vf[dt] = *reinterpret_cast<const short8*>(
            &sV[cur][row * 64 + (((c * 4 + l4) ^ (row & 7)) << 3)]);
      }
#pragma unroll
      for (int mt = 0; mt < 2; ++mt) {
        int q = mt * 16 + l15;
        pf[mt] = *reinterpret_cast<const short8*>(
            &sP[wid][q * 64 + (((c * 4 + l4) ^ (q & 7)) << 3)]);
      }
#pragma unroll
      for (int mt = 0; mt < 2; ++mt)
#pragma unroll
        for (int dt = 0; dt < 4; ++dt)
          oT[mt][dt] = __builtin_amdgcn_mfma_f32_16x16x32_bf16(
              vf[dt], pf[mt], oT[mt][dt], 0, 0, 0);
    }

    __syncthreads();
    cur ^= 1;
  }
#undef STAGE

  // epilogue: normalize, store O^T directly (8B stores; q=l15-indexed, d=l4-indexed)
#pragma unroll
  for (int mt = 0; mt < 2; ++mt) {
    float inv = 1.f / l_run[mt];
    int q = qr0 + mt * 16 + l15;
    short* orow = ob + (size_t)(b * NN + q) * EMBED + h * HD;
#pragma unroll
    for (int dt = 0; dt < 4; ++dt) {
      short4v o4;
#pragma unroll
      for (int r = 0; r < 4; ++r) o4[r] = f2bs(oT[mt][dt][r] * inv);
      *reinterpret_cast<short4v*>(orow + dt * 16 + l4 * 4) = o4;
    }
  }
}

extern "C" void kernel_launch(void* const* d_in, const int* in_sizes, int n_in,
                              void* d_out, int out_size, void* d_ws, size_t ws_size,
                              hipStream_t stream) {
  const float* x     = (const float*)d_in[0];
  const float* Wqkv  = (const float*)d_in[1];
  const float* bqkv  = (const float*)d_in[2];
  const float* Wproj = (const float*)d_in[3];
  const float* bproj = (const float*)d_in[4];
  float* out = (float*)d_out;

  char* ws = (char*)d_ws;
  const size_t SZ_X  = (size_t)MROWS * EMBED * 2;
  const size_t SZ_WQ = (size_t)QKV_COLS * EMBED * 2;
  const size_t SZ_WP = (size_t)EMBED * EMBED * 2;
  const size_t SZ_HB = (size_t)BB * NH * NN * HD * 2;
  if (ws_size < SZ_X * 2 + SZ_WQ + SZ_WP + SZ_HB * 3) return;

  short* xb     = (short*)ws;            ws += SZ_X;
  short* wqkvT  = (short*)ws;            ws += SZ_WQ;
  short* wprojT = (short*)ws;            ws += SZ_WP;
  short* qbuf   = (short*)ws;            ws += SZ_HB;
  short* kbuf   = (short*)ws;            ws += SZ_HB;
  short* vbufT  = (short*)ws;            ws += SZ_HB;   // [B,H,hd,N]
  short* aout   = (short*)ws;            ws += SZ_X;

  int n8 = MROWS * EMBED / 8;
  k_cvt<<<(n8 + 255) / 256, 256, 0, stream>>>(x, xb, n8);
  k_transpose_cvt<<<dim3(QKV_COLS / 32, EMBED / 32), dim3(32, 32), 0, stream>>>(
      Wqkv, wqkvT, EMBED, QKV_COLS);
  k_transpose_cvt<<<dim3(EMBED / 32, EMBED / 32), dim3(32, 32), 0, stream>>>(
      Wproj, wprojT, EMBED, EMBED);
  k_gemm_bt<0><<<dim3(MROWS / 128, QKV_COLS / 128), 256, 0, stream>>>(
      xb, wqkvT, bqkv, qbuf, kbuf, vbufT, nullptr, MROWS, QKV_COLS, EMBED);
  k_attn<<<dim3(NN / 128, BB * NH), 256, 0, stream>>>(qbuf, kbuf, vbufT, aout);
  k_gemm_bt<1><<<dim3(MROWS / 128, EMBED / 128), 256, 0, stream>>>(
      aout, wprojT, bproj, nullptr, nullptr, nullptr, out, MROWS, EMBED, EMBED);
}

// Round 4
// 206.373 us; speedup vs baseline: 1.4517x; 1.0361x over previous
//
#include <hip/hip_runtime.h>
#include <hip/hip_bf16.h>
#include <stdint.h>

using short4v = __attribute__((ext_vector_type(4))) short;
using short8  = __attribute__((ext_vector_type(8))) short;
using f32x4   = __attribute__((ext_vector_type(4))) float;

static constexpr int EMBED = 768;
static constexpr int NH    = 12;
static constexpr int HD    = 64;
static constexpr int BB    = 4;
static constexpr int NN    = 2048;
static constexpr int MROWS = BB * NN;          // 8192
static constexpr int QKV_COLS = 3 * EMBED;     // 2304
// Q prescale folds softmax scale AND log2(e) so P = exp2(S' - m')
static constexpr float QSCALE = 0.125f * 1.44269504088896340736f;

// round-to-nearest-even fp32 -> bf16 (bit path, used in cold kernels)
__device__ __forceinline__ short f2bs(float f) {
  unsigned int u = __float_as_uint(f);
  u += 0x7fffu + ((u >> 16) & 1u);
  return (short)(u >> 16);
}

// pack two fp32 -> two bf16 (RNE) via HIP cast; compiler fuses to v_cvt_pk_bf16_f32
__device__ __forceinline__ unsigned int pk2(float lo, float hi) {
  __hip_bfloat162 h = __float22bfloat162_rn(float2{lo, hi});
  return *reinterpret_cast<unsigned int*>(&h);
}

// raw 2^x
__device__ __forceinline__ float exp2a(float x) {
  float r;
  asm("v_exp_f32 %0, %1" : "=v"(r) : "v"(x));
  return r;
}

__device__ __forceinline__ void gload_lds16(const void* g, void* l) {
  __builtin_amdgcn_global_load_lds(
      (const __attribute__((address_space(1))) unsigned int*)g,
      (__attribute__((address_space(3))) unsigned int*)l, 16, 0, 0);
}

// ---------------- fp32 -> bf16 bulk convert (x) ----------------
__global__ void k_cvt(const float* __restrict__ in, short* __restrict__ out, int n8) {
  int i = blockIdx.x * blockDim.x + threadIdx.x;
  if (i >= n8) return;
  const float4* p = reinterpret_cast<const float4*>(in) + (size_t)i * 2;
  float4 a = p[0], b = p[1];
  short8 o;
  o[0] = f2bs(a.x); o[1] = f2bs(a.y); o[2] = f2bs(a.z); o[3] = f2bs(a.w);
  o[4] = f2bs(b.x); o[5] = f2bs(b.y); o[6] = f2bs(b.z); o[7] = f2bs(b.w);
  reinterpret_cast<short8*>(out)[i] = o;
}

// ---------------- fp32 [K][NC] -> bf16 [NC][K] transpose ----------------
__global__ void k_transpose_cvt(const float* __restrict__ in, short* __restrict__ out,
                                int K, int NC) {
  __shared__ float t[32][33];
  int n0 = blockIdx.x * 32, k0 = blockIdx.y * 32;
  t[threadIdx.y][threadIdx.x] = in[(size_t)(k0 + threadIdx.y) * NC + n0 + threadIdx.x];
  __syncthreads();
  out[(size_t)(n0 + threadIdx.y) * K + k0 + threadIdx.x] = f2bs(t[threadIdx.x][threadIdx.y]);
}

// ---------------- bf16 GEMM, C = A[M][K] * Bt[N][K]^T + bias ----------------
template <int EPI>
__global__ __launch_bounds__(256)
void k_gemm_bt(const short* __restrict__ A, const short* __restrict__ Bt,
               const float* __restrict__ bias,
               short* __restrict__ q_out, short* __restrict__ k_out,
               short* __restrict__ vT_out, float* __restrict__ f_out,
               int M, int NC, int K) {
  __shared__ short sA[128][32];
  __shared__ short sB[128][32];
  int tid = threadIdx.x;
  int lane = tid & 63, wid = tid >> 6;
  int wr = wid >> 1, wc = wid & 1;
  int l15 = lane & 15, l4 = lane >> 4;
  int mtile = blockIdx.x * 128, ntile = blockIdx.y * 128;

  f32x4 acc[4][4];
#pragma unroll
  for (int i = 0; i < 4; ++i)
#pragma unroll
    for (int j = 0; j < 4; ++j) acc[i][j] = (f32x4){0.f, 0.f, 0.f, 0.f};

  const int rA = lane >> 2;
  const int cA = (lane & 3) * 8;

  for (int kk = 0; kk < K; kk += 32) {
    __syncthreads();
#pragma unroll
    for (int p = 0; p < 2; ++p) {
      int r0 = p * 64 + wid * 16;
      gload_lds16(A  + (size_t)(mtile + r0 + rA) * K + kk + cA, &sA[r0][0]);
      gload_lds16(Bt + (size_t)(ntile + r0 + rA) * K + kk + cA, &sB[r0][0]);
    }
    __syncthreads();
    short8 af[4], bfr[4];
#pragma unroll
    for (int i = 0; i < 4; ++i)
      af[i] = *reinterpret_cast<const short8*>(&sA[wr * 64 + i * 16 + l15][l4 * 8]);
#pragma unroll
    for (int j = 0; j < 4; ++j)
      bfr[j] = *reinterpret_cast<const short8*>(&sB[wc * 64 + j * 16 + l15][l4 * 8]);
#pragma unroll
    for (int i = 0; i < 4; ++i)
#pragma unroll
      for (int j = 0; j < 4; ++j)
        acc[i][j] = __builtin_amdgcn_mfma_f32_16x16x32_bf16(af[i], bfr[j], acc[i][j], 0, 0, 0);
  }

#pragma unroll
  for (int i = 0; i < 4; ++i) {
#pragma unroll
    for (int j = 0; j < 4; ++j) {
      int col = ntile + wc * 64 + j * 16 + l15;
      float bcol = bias[col];
      float vv[4];
#pragma unroll
      for (int r = 0; r < 4; ++r) vv[r] = acc[i][j][r] + bcol;
      if (EPI == 0) {
        int s = col / EMBED;
        int rem = col - s * EMBED;
        int hh = rem >> 6, d = rem & 63;
        int row0 = mtile + wr * 64 + i * 16 + l4 * 4;
        int b2 = row0 >> 11, n0 = row0 & 2047;
        if (s == 0) {
#pragma unroll
          for (int r = 0; r < 4; ++r)
            q_out[(size_t)((b2 * NH + hh) * NN + n0 + r) * HD + d] =
                f2bs(vv[r] * QSCALE);
        } else if (s == 1) {
#pragma unroll
          for (int r = 0; r < 4; ++r)
            k_out[(size_t)((b2 * NH + hh) * NN + n0 + r) * HD + d] = f2bs(vv[r]);
        } else {
          short4v o;
#pragma unroll
          for (int r = 0; r < 4; ++r) o[r] = f2bs(vv[r]);
          *reinterpret_cast<short4v*>(
              &vT_out[((size_t)(b2 * NH + hh) * HD + d) * NN + n0]) = o;
        }
      } else {
        int row0 = mtile + wr * 64 + i * 16 + l4 * 4;
#pragma unroll
        for (int r = 0; r < 4; ++r)
          f_out[(size_t)(row0 + r) * NC + col] = vv[r];
      }
    }
  }
}

// ---------------- flash attention (swapped-QK^T, O^T accum) ----------------
// grid 768 blocks (XCD-swizzled); 4 waves, 32 q-rows/wave, KVBLK=64, dbuf K/V^T
__global__ __launch_bounds__(256)
void k_attn(const short* __restrict__ qb, const short* __restrict__ kb,
            const short* __restrict__ vtb, short* __restrict__ ob) {
  __shared__ __align__(16) short sK[2][64 * 64];   // [kv][d], src-pre-swizzled
  __shared__ __align__(16) short sV[2][64 * 64];   // V^T [d][kv], src-pre-swizzled
  __shared__ __align__(16) short sPc[4][32 * 32];  // per-wave P[q][kv32 half]

  const int tid = threadIdx.x, lane = tid & 63, wid = tid >> 6;
  const int l15 = lane & 15, l4 = lane >> 4;

  // XCD-chunked swizzle: 768 blocks = 8 XCDs x 96; keep one head's q-tiles together
  const int flat = blockIdx.x + (int)gridDim.x * blockIdx.y;
  const int swz  = (flat & 7) * 96 + (flat >> 3);
  const int bh   = swz >> 4, b = bh / NH, h = bh % NH;
  const int qr0  = (swz & 15) * 128 + wid * 32;

  const short* Q  = qb  + (size_t)bh * NN * HD;
  const short* Kp = kb  + (size_t)bh * NN * HD;
  const short* Vt = vtb + (size_t)bh * HD * NN;

  const int sr  = lane >> 3;
  const int sc8 = lane & 7;

  short8 qf[2][2];
#pragma unroll
  for (int mt = 0; mt < 2; ++mt)
#pragma unroll
    for (int c = 0; c < 2; ++c)
      qf[mt][c] = *reinterpret_cast<const short8*>(
          Q + (size_t)(qr0 + mt * 16 + l15) * HD + c * 32 + l4 * 8);

  f32x4 oT[2][4];
  float m_run[2], l_run[2];
#pragma unroll
  for (int mt = 0; mt < 2; ++mt) {
    m_run[mt] = -1e30f; l_run[mt] = 0.f;
#pragma unroll
    for (int dt = 0; dt < 4; ++dt) oT[mt][dt] = (f32x4){0.f, 0.f, 0.f, 0.f};
  }

#define STAGE(BUF, KV0)                                                          \
  {                                                                              \
    _Pragma("unroll")                                                            \
    for (int i_ = 0; i_ < 2; ++i_) {                                             \
      int r_ = wid * 16 + i_ * 8 + sr;                                           \
      int cs_ = (sc8 ^ (r_ & 7)) << 3;                                           \
      gload_lds16(Kp + (size_t)((KV0) + r_) * HD + cs_,                          \
                  &sK[BUF][(wid * 16 + i_ * 8) * 64]);                           \
      gload_lds16(Vt + (size_t)r_ * NN + (KV0) + cs_,                            \
                  &sV[BUF][(wid * 16 + i_ * 8) * 64]);                           \
    }                                                                            \
  }

  int cur = 0;
  STAGE(0, 0);
  __syncthreads();

  for (int t = 0; t < NN / 64; ++t) {
    if (t + 1 < NN / 64) STAGE(cur ^ 1, (t + 1) * 64);

    // S^T = mfma(K rows, Q rows): sa[mt][nt][r] = S[q=mt*16+l15][kv=nt*16+l4*4+r]
    f32x4 sa[2][4];
#pragma unroll
    for (int mt = 0; mt < 2; ++mt)
#pragma unroll
      for (int nt = 0; nt < 4; ++nt) sa[mt][nt] = (f32x4){0.f, 0.f, 0.f, 0.f};
    __builtin_amdgcn_s_setprio(1);
#pragma unroll
    for (int c = 0; c < 2; ++c) {
      short8 kf[4];
#pragma unroll
      for (int nt = 0; nt < 4; ++nt) {
        int row = nt * 16 + l15;
        kf[nt] = *reinterpret_cast<const short8*>(
            &sK[cur][row * 64 + (((c * 4 + l4) ^ (row & 7)) << 3)]);
      }
#pragma unroll
      for (int mt = 0; mt < 2; ++mt)
#pragma unroll
        for (int nt = 0; nt < 4; ++nt)
          sa[mt][nt] = __builtin_amdgcn_mfma_f32_16x16x32_bf16(
              kf[nt], qf[mt][c], sa[mt][nt], 0, 0, 0);
    }
    __builtin_amdgcn_s_setprio(0);

    // online softmax in exp2 domain; defer-max (THR=8 -> P <= 256)
#pragma unroll
    for (int mt = 0; mt < 2; ++mt) {
      float mx = sa[mt][0][0];
#pragma unroll
      for (int nt = 0; nt < 4; ++nt)
#pragma unroll
        for (int r = 0; r < 4; ++r) mx = fmaxf(mx, sa[mt][nt][r]);
      mx = fmaxf(mx, __shfl_xor(mx, 16));
      mx = fmaxf(mx, __shfl_xor(mx, 32));
      if (!__all(mx <= m_run[mt] + 8.f)) {
        float mnew = fmaxf(m_run[mt], mx);
        float sc = exp2a(m_run[mt] - mnew);
        l_run[mt] *= sc;
        m_run[mt] = mnew;
#pragma unroll
        for (int dt = 0; dt < 4; ++dt) {
          oT[mt][dt][0] *= sc; oT[mt][dt][1] *= sc;
          oT[mt][dt][2] *= sc; oT[mt][dt][3] *= sc;
        }
      }
      float ps = 0.f;
#pragma unroll
      for (int nt = 0; nt < 4; ++nt)
#pragma unroll
        for (int r = 0; r < 4; ++r) {
          float p = exp2a(sa[mt][nt][r] - m_run[mt]);
          sa[mt][nt][r] = p;
          ps += p;
        }
      ps += __shfl_xor(ps, 16);
      ps += __shfl_xor(ps, 32);
      l_run[mt] += ps;
    }

    // PV in two kv-32 halves through the 2KB/wave sPc slab
#pragma unroll
    for (int c = 0; c < 2; ++c) {
#pragma unroll
      for (int mt = 0; mt < 2; ++mt) {
        int q = mt * 16 + l15;
#pragma unroll
        for (int nl = 0; nl < 2; ++nl) {
          int nt = c * 2 + nl;
          uint2 wv;
          wv.x = pk2(sa[mt][nt][0], sa[mt][nt][1]);
          wv.y = pk2(sa[mt][nt][2], sa[mt][nt][3]);
          int ch0 = nl * 2 + (l4 >> 1);
          *reinterpret_cast<uint2*>(
              (char*)&sPc[wid][0] + q * 64 + ((ch0 ^ (q & 3)) << 4) + (l4 & 1) * 8) = wv;
        }
      }
      short8 vf[4], pf[2];
#pragma unroll
      for (int dt = 0; dt < 4; ++dt) {
        int row = dt * 16 + l15;
        vf[dt] = *reinterpret_cast<const short8*>(
            &sV[cur][row * 64 + (((c * 4 + l4) ^ (row & 7)) << 3)]);
      }
#pragma unroll
      for (int mt = 0; mt < 2; ++mt) {
        int q = mt * 16 + l15;
        pf[mt] = *reinterpret_cast<const short8*>(
            (char*)&sPc[wid][0] + q * 64 + ((l4 ^ (q & 3)) << 4));
      }
      __builtin_amdgcn_s_setprio(1);
#pragma unroll
      for (int mt = 0; mt < 2; ++mt)
#pragma unroll
        for (int dt = 0; dt < 4; ++dt)
          oT[mt][dt] = __builtin_amdgcn_mfma_f32_16x16x32_bf16(
              vf[dt], pf[mt], oT[mt][dt], 0, 0, 0);
      __builtin_amdgcn_s_setprio(0);
    }

    __syncthreads();
    cur ^= 1;
  }
#undef STAGE

  // epilogue: normalize, store O^T directly (8B stores)
#pragma unroll
  for (int mt = 0; mt < 2; ++mt) {
    float inv = 1.f / l_run[mt];
    int q = qr0 + mt * 16 + l15;
    short* orow = ob + (size_t)(b * NN + q) * EMBED + h * HD;
#pragma unroll
    for (int dt = 0; dt < 4; ++dt) {
      uint2 u;
      u.x = pk2(oT[mt][dt][0] * inv, oT[mt][dt][1] * inv);
      u.y = pk2(oT[mt][dt][2] * inv, oT[mt][dt][3] * inv);
      *reinterpret_cast<uint2*>(orow + dt * 16 + l4 * 4) = u;
    }
  }
}

extern "C" void kernel_launch(void* const* d_in, const int* in_sizes, int n_in,
                              void* d_out, int out_size, void* d_ws, size_t ws_size,
                              hipStream_t stream) {
  const float* x     = (const float*)d_in[0];
  const float* Wqkv  = (const float*)d_in[1];
  const float* bqkv  = (const float*)d_in[2];
  const float* Wproj = (const float*)d_in[3];
  const float* bproj = (const float*)d_in[4];
  float* out = (float*)d_out;

  char* ws = (char*)d_ws;
  const size_t SZ_X  = (size_t)MROWS * EMBED * 2;
  const size_t SZ_WQ = (size_t)QKV_COLS * EMBED * 2;
  const size_t SZ_WP = (size_t)EMBED * EMBED * 2;
  const size_t SZ_HB = (size_t)BB * NH * NN * HD * 2;
  if (ws_size < SZ_X * 2 + SZ_WQ + SZ_WP + SZ_HB * 3) return;

  short* xb     = (short*)ws;            ws += SZ_X;
  short* wqkvT  = (short*)ws;            ws += SZ_WQ;
  short* wprojT = (short*)ws;            ws += SZ_WP;
  short* qbuf   = (short*)ws;            ws += SZ_HB;
  short* kbuf   = (short*)ws;            ws += SZ_HB;
  short* vbufT  = (short*)ws;            ws += SZ_HB;   // [B,H,hd,N]
  short* aout   = (short*)ws;            ws += SZ_X;

  int n8 = MROWS * EMBED / 8;
  k_cvt<<<(n8 + 255) / 256, 256, 0, stream>>>(x, xb, n8);
  k_transpose_cvt<<<dim3(QKV_COLS / 32, EMBED / 32), dim3(32, 32), 0, stream>>>(
      Wqkv, wqkvT, EMBED, QKV_COLS);
  k_transpose_cvt<<<dim3(EMBED / 32, EMBED / 32), dim3(32, 32), 0, stream>>>(
      Wproj, wprojT, EMBED, EMBED);
  k_gemm_bt<0><<<dim3(MROWS / 128, QKV_COLS / 128), 256, 0, stream>>>(
      xb, wqkvT, bqkv, qbuf, kbuf, vbufT, nullptr, MROWS, QKV_COLS, EMBED);
  k_attn<<<dim3(NN / 128, BB * NH), 256, 0, stream>>>(qbuf, kbuf, vbufT, aout);
  k_gemm_bt<1><<<dim3(MROWS / 128, EMBED / 128), 256, 0, stream>>>(
      aout, wprojT, bproj, nullptr, nullptr, nullptr, out, MROWS, EMBED, EMBED);
}